// Round 1
// baseline (292.573 us; speedup 1.0000x reference)
//
#include <hip/hip_runtime.h>
#include <hip/hip_bf16.h>

#define N_NODES 50000
#define IN_CH 128
#define HID 128
#define OUT_CH 64
#define N_EDGES 800000
#define N_TOT_EDGES (N_EDGES + N_NODES)   // + self loops

// ---------------- CSR build ----------------

__global__ void k_init_cnt(int* cnt, int n) {
    int i = blockIdx.x * 256 + threadIdx.x;
    if (i < n) cnt[i] = 1;   // self-loop contributes 1 to every node
}

__global__ void k_count(const int* __restrict__ dst_row, int* __restrict__ cnt, int e) {
    int i = blockIdx.x * 256 + threadIdx.x;
    if (i < e) atomicAdd(&cnt[dst_row[i]], 1);
}

// inclusive scan of cnt -> off[i+1]; per-block sums to bsum
__global__ void k_scan1(const int* __restrict__ cnt, int* __restrict__ off,
                        int* __restrict__ bsum, int n) {
    __shared__ int s[256];
    int t = threadIdx.x;
    int i = blockIdx.x * 256 + t;
    int v = (i < n) ? cnt[i] : 0;
    s[t] = v;
    __syncthreads();
    for (int d = 1; d < 256; d <<= 1) {
        int x = (t >= d) ? s[t - d] : 0;
        __syncthreads();
        s[t] += x;
        __syncthreads();
    }
    if (i < n) off[i + 1] = s[t];
    if (t == 255) bsum[blockIdx.x] = s[255];
}

__global__ void k_scan2(int* __restrict__ bsum, int nb) {  // single block, nb <= 256
    __shared__ int s[256];
    int t = threadIdx.x;
    int v = (t < nb) ? bsum[t] : 0;
    s[t] = v;
    __syncthreads();
    for (int d = 1; d < 256; d <<= 1) {
        int x = (t >= d) ? s[t - d] : 0;
        __syncthreads();
        s[t] += x;
        __syncthreads();
    }
    if (t < nb) bsum[t] = s[t] - v;  // exclusive prefix
}

__global__ void k_scan3(int* __restrict__ off, const int* __restrict__ bsum, int n) {
    int i = blockIdx.x * 256 + threadIdx.x;
    if (i < n) off[i + 1] += bsum[blockIdx.x];
    if (i == 0) off[0] = 0;
}

__global__ void k_fill(const int* __restrict__ ei, const int* __restrict__ off,
                       int* __restrict__ cur, int* __restrict__ csr, int e, int n) {
    int i = blockIdx.x * 256 + threadIdx.x;
    if (i >= e + n) return;
    int src, dst;
    if (i < e) { src = ei[i]; dst = ei[e + i]; }
    else       { src = dst = i - e; }
    int pos = off[dst] + atomicAdd(&cur[dst], 1);
    csr[pos] = src;
}

// ---------------- GEMM (h = X @ W) + fused attention dots ----------------
// Each thread computes 4 rows x 4 cols. W staged fully in LDS.
template<int N>
__global__ __launch_bounds__(256) void gemm_att(
        const float* __restrict__ X, const float* __restrict__ W,
        const float* __restrict__ asrc, const float* __restrict__ adst,
        float* __restrict__ H, float* __restrict__ als, float* __restrict__ ald,
        int M) {
    constexpr int K = 128;
    constexpr int TPR = N / 4;             // threads per row (32 or 16)
    constexpr int RPB = (256 / TPR) * 4;   // rows per block (32 or 64)
    __shared__ float Ws[K * N];
    __shared__ float Xs[RPB * K];
    const int t = threadIdx.x;
    const int r0 = blockIdx.x * RPB;

    for (int i = t * 4; i < K * N; i += 256 * 4)
        *(float4*)&Ws[i] = *(const float4*)&W[i];
    for (int i = t * 4; i < RPB * K; i += 256 * 4) {
        int row = r0 + i / K;
        float4 v = make_float4(0.f, 0.f, 0.f, 0.f);
        if (row < M) v = *(const float4*)&X[(size_t)r0 * K + i];
        *(float4*)&Xs[i] = v;
    }
    __syncthreads();

    const int col = (t % TPR) * 4;
    const int rg  = (t / TPR) * 4;
    float acc[4][4] = {};
    for (int k = 0; k < K; ++k) {
        float4 wv = *(const float4*)&Ws[k * N + col];
        #pragma unroll
        for (int r = 0; r < 4; ++r) {
            float xv = Xs[(rg + r) * K + k];
            acc[r][0] += xv * wv.x;
            acc[r][1] += xv * wv.y;
            acc[r][2] += xv * wv.z;
            acc[r][3] += xv * wv.w;
        }
    }

    float as0 = asrc[col], as1 = asrc[col+1], as2 = asrc[col+2], as3 = asrc[col+3];
    float ad0 = adst[col], ad1 = adst[col+1], ad2 = adst[col+2], ad3 = adst[col+3];
    #pragma unroll
    for (int r = 0; r < 4; ++r) {
        int row = r0 + rg + r;
        float ps = acc[r][0]*as0 + acc[r][1]*as1 + acc[r][2]*as2 + acc[r][3]*as3;
        float pd = acc[r][0]*ad0 + acc[r][1]*ad1 + acc[r][2]*ad2 + acc[r][3]*ad3;
        #pragma unroll
        for (int mask = 1; mask < TPR; mask <<= 1) {
            ps += __shfl_xor(ps, mask);
            pd += __shfl_xor(pd, mask);
        }
        if (row < M) {
            *(float4*)&H[(size_t)row * N + col] =
                make_float4(acc[r][0], acc[r][1], acc[r][2], acc[r][3]);
            if ((t % TPR) == 0) { als[row] = ps; ald[row] = pd; }
        }
    }
}

// ---------------- Per-dst-node softmax + weighted aggregation ----------------
// One wave (64 lanes) per node; no atomics.
template<int F, bool RELU>
__global__ __launch_bounds__(256) void k_agg(
        const float* __restrict__ H, const float* __restrict__ als,
        const float* __restrict__ ald, const float* __restrict__ bias,
        const int* __restrict__ off, const int* __restrict__ csr,
        float* __restrict__ out, int n) {
    const int lane = threadIdx.x & 63;
    const int v = blockIdx.x * 4 + (threadIdx.x >> 6);
    if (v >= n) return;
    const int start = off[v], end = off[v + 1];
    const float aldv = ald[v];

    // pass 1: segment max of leaky_relu scores
    float m = -1e30f;
    for (int j = start + lane; j < end; j += 64) {
        float e = als[csr[j]] + aldv;
        e = e > 0.f ? e : 0.2f * e;
        m = fmaxf(m, e);
    }
    #pragma unroll
    for (int d = 32; d; d >>= 1) m = fmaxf(m, __shfl_xor(m, d));

    // pass 2: denom + weighted sum of h[src]
    float denom = 0.f;
    float a0 = 0.f, a1 = 0.f;
    for (int base = start; base < end; base += 64) {
        int j = base + lane;
        int s = 0;
        float w = 0.f;
        if (j < end) {
            s = csr[j];
            float e = als[s] + aldv;
            e = e > 0.f ? e : 0.2f * e;
            w = __expf(e - m);
        }
        int nn = min(64, end - base);
        for (int i = 0; i < nn; ++i) {
            float wi = __shfl(w, i);
            int   si = __shfl(s, i);
            if (F == 128) {
                float2 hv = *(const float2*)&H[(size_t)si * 128 + lane * 2];
                a0 += hv.x * wi;
                a1 += hv.y * wi;
            } else {
                a0 += H[(size_t)si * 64 + lane] * wi;
            }
            denom += wi;
        }
    }
    float inv = 1.f / (denom + 1e-16f);
    if (F == 128) {
        float o0 = a0 * inv + bias[lane * 2];
        float o1 = a1 * inv + bias[lane * 2 + 1];
        if (RELU) { o0 = fmaxf(o0, 0.f); o1 = fmaxf(o1, 0.f); }
        *(float2*)&out[(size_t)v * 128 + lane * 2] = make_float2(o0, o1);
    } else {
        float o = a0 * inv + bias[lane];
        if (RELU) o = fmaxf(o, 0.f);
        out[(size_t)v * 64 + lane] = o;
    }
}

// ---------------- launch ----------------

extern "C" void kernel_launch(void* const* d_in, const int* in_sizes, int n_in,
                              void* d_out, int out_size, void* d_ws, size_t ws_size,
                              hipStream_t stream) {
    const float* x     = (const float*)d_in[0];
    const int*   ei    = (const int*)d_in[1];
    const float* W1    = (const float*)d_in[2];
    const float* as1   = (const float*)d_in[3];
    const float* ad1   = (const float*)d_in[4];
    const float* b1    = (const float*)d_in[5];
    const float* W2    = (const float*)d_in[6];
    const float* as2   = (const float*)d_in[7];
    const float* ad2   = (const float*)d_in[8];
    const float* b2    = (const float*)d_in[9];
    float* out = (float*)d_out;

    const int Nn = N_NODES, E = N_EDGES, ET = N_TOT_EDGES;

    // workspace carve-up (256B aligned)
    char* ws = (char*)d_ws;
    size_t o = 0;
    auto carve = [&](size_t bytes) { char* p = ws + o; o = (o + bytes + 255) & ~(size_t)255; return p; };
    int*   off  = (int*)carve((Nn + 1) * sizeof(int));
    int*   cnt  = (int*)carve(Nn * sizeof(int));
    int*   cur  = (int*)carve(Nn * sizeof(int));
    int*   bsum = (int*)carve(256 * sizeof(int));
    int*   csr  = (int*)carve((size_t)ET * sizeof(int));
    float* h1   = (float*)carve((size_t)Nn * HID * sizeof(float));   // reused as h2
    float* als  = (float*)carve(Nn * sizeof(float));
    float* ald  = (float*)carve(Nn * sizeof(float));
    float* y1   = (float*)carve((size_t)Nn * HID * sizeof(float));
    float* h2   = h1;

    const int nbN  = (Nn + 255) / 256;       // 196
    const int nbE  = (E + 255) / 256;
    const int nbET = (ET + 255) / 256;

    // CSR build
    k_init_cnt<<<nbN, 256, 0, stream>>>(cnt, Nn);
    k_count<<<nbE, 256, 0, stream>>>(ei + E, cnt, E);
    k_scan1<<<nbN, 256, 0, stream>>>(cnt, off, bsum, Nn);
    k_scan2<<<1, 256, 0, stream>>>(bsum, nbN);
    k_scan3<<<nbN, 256, 0, stream>>>(off, bsum, Nn);
    hipMemsetAsync(cur, 0, Nn * sizeof(int), stream);
    k_fill<<<nbET, 256, 0, stream>>>(ei, off, cur, csr, E, Nn);

    // layer 1
    gemm_att<HID><<<(Nn + 31) / 32, 256, 0, stream>>>(x, W1, as1, ad1, h1, als, ald, Nn);
    k_agg<HID, true><<<(Nn + 3) / 4, 256, 0, stream>>>(h1, als, ald, b1, off, csr, y1, Nn);

    // layer 2
    gemm_att<OUT_CH><<<(Nn + 63) / 64, 256, 0, stream>>>(y1, W2, as2, ad2, h2, als, ald, Nn);
    k_agg<OUT_CH, false><<<(Nn + 3) / 4, 256, 0, stream>>>(h2, als, ald, b2, off, csr, out, Nn);
}